// Round 11
// baseline (432.339 us; speedup 1.0000x reference)
//
#include <hip/hip_runtime.h>
#include <math.h>

#define NN 100000
#define NE 1600000      // edges WITHOUT self-loops; self-loop handled analytically
#define ICH 128
#define HID 64
#define NGR 64
#define NB_SCAN 391     // ceil(100000/256)

__device__ __forceinline__ float lrelu(float x){ return x > 0.f ? x : 0.2f*x; }
__device__ __forceinline__ float eluf(float x){ return x > 0.f ? x : expm1f(x); }

__device__ __forceinline__ float bf2f(unsigned short u){
  return __uint_as_float(((unsigned int)u) << 16);
}
__device__ __forceinline__ unsigned short f2bf(float f){   // RNE
  unsigned int u = __float_as_uint(f);
  return (unsigned short)((u + 0x7FFF + ((u >> 16) & 1)) >> 16);
}

__device__ __forceinline__ float wsum64(float v){
  #pragma unroll
  for (int m = 32; m >= 1; m >>= 1) v += __shfl_xor(v, m);
  return v;
}
__device__ __forceinline__ float wsum16(float v){
  v += __shfl_xor(v, 8); v += __shfl_xor(v, 4);
  v += __shfl_xor(v, 2); v += __shfl_xor(v, 1);
  return v;
}
__device__ __forceinline__ int wscan_incl(int v){
  const int lane = threadIdx.x & 63;
  #pragma unroll
  for (int d = 1; d < 64; d <<= 1){
    int t = __shfl_up(v, d);
    if (lane >= d) v += t;
  }
  return v;
}

// ---------------- CSR build ----------------
// deg: 4 dst-windows (100KB hot set per window; 4x edge re-read L3-served).
__global__ __launch_bounds__(256) void k_deg(const int* __restrict__ ei_dst,
                                             int* __restrict__ deg)
{
  const int lo = (blockIdx.x & 3) * 25000, hi = lo + 25000;
  const int nb = gridDim.x >> 2, ib = blockIdx.x >> 2;
  for (int e = ib * 256 + threadIdx.x; e < NE; e += nb * 256){
    int d = ei_dst[e];
    if (d >= lo && d < hi) atomicAdd(&deg[d], 1);
  }
}

__global__ __launch_bounds__(256) void k_scanA(const int* __restrict__ deg,
    int* __restrict__ rowptr, int* __restrict__ bsum)
{
  int i = blockIdx.x * 256 + threadIdx.x;
  int v = (i < NN) ? deg[i] : 0;
  int incl = wscan_incl(v);
  __shared__ int wsums[4];
  int w = threadIdx.x >> 6, lane = threadIdx.x & 63;
  if (lane == 63) wsums[w] = incl;
  __syncthreads();
  int off = 0;
  for (int k = 0; k < w; ++k) off += wsums[k];
  if (i < NN) rowptr[i] = incl - v + off;
  if (threadIdx.x == 255) bsum[blockIdx.x] = off + incl;
}

__global__ __launch_bounds__(512) void k_scanB(const int* __restrict__ bsum,
                                               int* __restrict__ boff)
{
  int i = threadIdx.x;
  int v = (i < NB_SCAN) ? bsum[i] : 0;
  int incl = wscan_incl(v);
  __shared__ int wsums[8];
  int w = threadIdx.x >> 6, lane = threadIdx.x & 63;
  if (lane == 63) wsums[w] = incl;
  __syncthreads();
  int off = 0;
  for (int k = 0; k < w; ++k) off += wsums[k];
  if (i < NB_SCAN) boff[i] = incl - v + off;
}

__global__ __launch_bounds__(256) void k_scanC(int* __restrict__ rowptr,
    const int* __restrict__ boff, int* __restrict__ cursor)
{
  int i = blockIdx.x * 256 + threadIdx.x;
  if (i < NN){
    int val = rowptr[i] + boff[blockIdx.x];
    rowptr[i] = val;
    cursor[i] = val;
  }
  if (i == 0) rowptr[NN] = NE;
}

// scatter: 8 dst-windows -> target region ~800KB stays in one XCD's L2.
__global__ __launch_bounds__(256) void k_scatter(const int* __restrict__ ei,
    int* __restrict__ cursor, int* __restrict__ csr_src)
{
  const int lo = (blockIdx.x & 7) * 12500, hi = lo + 12500;
  const int nb = gridDim.x >> 3, ib = blockIdx.x >> 3;
  for (int e = ib * 256 + threadIdx.x; e < NE; e += nb * 256){
    int d = ei[NE + e];
    if (d >= lo && d < hi){
      int pos = atomicAdd(&cursor[d], 1);
      csr_src[pos] = ei[e];
    }
  }
}

// ---------------- dense node kernels ----------------
// h1 = x @ W1 + per-head attention logits. x tile AND W1 (32KB) in LDS.
__global__ __launch_bounds__(256) void k_gemm1(const float* __restrict__ x,
    const float* __restrict__ W1, const float* __restrict__ asw,
    const float* __restrict__ adw, unsigned short* __restrict__ h1b,
    float* __restrict__ as1, float* __restrict__ ad1)
{
  __shared__ float xs[16 * ICH];            // 8 KB
  __shared__ float w1s[ICH * HID];          // 32 KB
  const int t = threadIdx.x;
  const int n0 = blockIdx.x * 16;
  const float4* xg4 = (const float4*)(x + (size_t)n0 * ICH);
  float4* xs4 = (float4*)xs;
  xs4[t]       = xg4[t];
  xs4[t + 256] = xg4[t + 256];
  const float4* wg4 = (const float4*)W1;
  float4* ws4 = (float4*)w1s;
  #pragma unroll
  for (int i = 0; i < 8; ++i) ws4[t + 256 * i] = wg4[t + 256 * i];
  __syncthreads();

  const int lane = t & 63;
  const float* xr = xs + (t >> 6) * 4 * ICH;   // wave's 4 rows
  float a0 = 0.f, a1 = 0.f, a2 = 0.f, a3 = 0.f;
  #pragma unroll 8
  for (int k = 0; k < ICH; ++k){
    const float w = w1s[k * HID + lane];
    a0 = fmaf(xr[k],          w, a0);
    a1 = fmaf(xr[ICH + k],    w, a1);
    a2 = fmaf(xr[2*ICH + k],  w, a2);
    a3 = fmaf(xr[3*ICH + k],  w, a3);
  }
  const float sw = asw[lane], dw = adw[lane];  // att layout [H][16] flattens to [64]
  const int nw = n0 + (t >> 6) * 4;
  float acc[4] = {a0, a1, a2, a3};
  #pragma unroll
  for (int i = 0; i < 4; ++i){
    const int n = nw + i;
    h1b[(size_t)n * HID + lane] = f2bf(acc[i]);
    float ps = wsum16(acc[i] * sw);
    float pd = wsum16(acc[i] * dw);
    if ((lane & 15) == 0){
      as1[n * 4 + (lane >> 4)] = ps;
      ad1[n * 4 + (lane >> 4)] = pd;
    }
  }
}

// conv1 (r8 best): batched edges (16/batch x 4 heads), LDS {e,s} park,
// 4x-unrolled broadcast loop, self-loop analytic, normalize after sum.
__global__ __launch_bounds__(256) void k_conv1(const int* __restrict__ rowptr,
    const int* __restrict__ csr_src, const float* __restrict__ as1,
    const float* __restrict__ ad1, const unsigned short* __restrict__ h1b,
    const float* __restrict__ b1, float* __restrict__ hb)
{
  __shared__ float2 buf[256];               // 64 entries per wave
  const int t = threadIdx.x;
  const int lane = t & 63;
  const int h = lane >> 4;                  // head
  const int m = lane & 15;                  // edge slot within batch
  const int woff = t & 192;                 // wave's LDS window base
  const int n = (blockIdx.x * 256 + t) >> 6;
  const int row0 = __builtin_amdgcn_readfirstlane(rowptr[n]);
  const int row1 = __builtin_amdgcn_readfirstlane(rowptr[n + 1]);
  const float adh = ad1[4 * n + h];
  const float eself = __expf(lrelu(as1[4 * n + h] + adh));   // self-loop
  const unsigned short* __restrict__ hrow = h1b + lane;
  float a0 = eself * bf2f(hrow[(unsigned)n << 6]);
  float a1 = 0.f, a2 = 0.f, a3 = 0.f;
  float den_p = 0.f;
  const int rbase = woff + (lane & 48);     // = woff + h*16
  for (int base = row0; base < row1; base += 16){
    const int cnt = min(16, row1 - base);
    int s = 0; float e = 0.f;
    if (m < cnt){
      s = csr_src[base + m];
      e = __expf(lrelu(as1[4 * s + h] + adh));
    }
    den_p += e;
    buf[woff + lane] = make_float2(e, __int_as_float(s));
    // same-wave RAW: compiler orders via lgkmcnt; buffer is wave-private.
    int j = 0;
    for (; j + 4 <= cnt; j += 4){
      float2 p0 = buf[rbase + j];
      float2 p1 = buf[rbase + j + 1];
      float2 p2 = buf[rbase + j + 2];
      float2 p3 = buf[rbase + j + 3];
      float v0 = bf2f(hrow[(unsigned)__float_as_int(p0.y) << 6]);
      float v1 = bf2f(hrow[(unsigned)__float_as_int(p1.y) << 6]);
      float v2 = bf2f(hrow[(unsigned)__float_as_int(p2.y) << 6]);
      float v3 = bf2f(hrow[(unsigned)__float_as_int(p3.y) << 6]);
      a0 = fmaf(v0, p0.x, a0);
      a1 = fmaf(v1, p1.x, a1);
      a2 = fmaf(v2, p2.x, a2);
      a3 = fmaf(v3, p3.x, a3);
    }
    for (; j < cnt; ++j){
      float2 p0 = buf[rbase + j];
      a0 = fmaf(bf2f(hrow[(unsigned)__float_as_int(p0.y) << 6]), p0.x, a0);
    }
  }
  float acc = (a0 + a1) + (a2 + a3);
  float den = wsum16(den_p) + eself;
  float o = acc / (den + 1e-16f) + b1[lane];
  hb[((size_t)n << 6) | lane] = eluf(o);
}

// h2 = h @ W2 (64x64) + scalar-head attention logits; h tile AND W2 in LDS.
__global__ __launch_bounds__(256) void k_gemm2(const float* __restrict__ h,
    const float* __restrict__ W2, const float* __restrict__ asw,
    const float* __restrict__ adw, unsigned short* __restrict__ h2b,
    float* __restrict__ as2, float* __restrict__ ad2)
{
  __shared__ float hs[16 * HID];            // 4 KB
  __shared__ float w2s[HID * HID];          // 16 KB
  const int t = threadIdx.x;
  const int n0 = blockIdx.x * 16;
  const float4* hg4 = (const float4*)(h + (size_t)n0 * HID);
  float4* hs4 = (float4*)hs;
  hs4[t] = hg4[t];
  const float4* wg4 = (const float4*)W2;
  float4* ws4 = (float4*)w2s;
  #pragma unroll
  for (int i = 0; i < 4; ++i) ws4[t + 256 * i] = wg4[t + 256 * i];
  __syncthreads();

  const int lane = t & 63;
  const float* hr = hs + (t >> 6) * 4 * HID;
  float a0 = 0.f, a1 = 0.f, a2 = 0.f, a3 = 0.f;
  #pragma unroll 8
  for (int k = 0; k < HID; ++k){
    const float w = w2s[k * HID + lane];
    a0 = fmaf(hr[k],          w, a0);
    a1 = fmaf(hr[HID + k],    w, a1);
    a2 = fmaf(hr[2*HID + k],  w, a2);
    a3 = fmaf(hr[3*HID + k],  w, a3);
  }
  const float sw = asw[lane], dw = adw[lane];
  const int nw = n0 + (t >> 6) * 4;
  float acc[4] = {a0, a1, a2, a3};
  #pragma unroll
  for (int i = 0; i < 4; ++i){
    const int n = nw + i;
    h2b[(size_t)n * HID + lane] = f2bf(acc[i]);
    float ps = wsum64(acc[i] * sw);
    float pd = wsum64(acc[i] * dw);
    if (lane == 0){ as2[n] = ps; ad2[n] = pd; }
  }
}

// conv2 (r8 best): batched edges (64/batch) + 4x unroll + fused residual +
// LayerNorm + elu + pool logit. hf aliases hb (own-row RAW only).
__global__ __launch_bounds__(256) void k_conv2(const int* __restrict__ rowptr,
    const int* __restrict__ csr_src, const float* __restrict__ as2,
    const float* __restrict__ ad2, const unsigned short* __restrict__ h2b,
    const float* __restrict__ b2, float* __restrict__ hb,
    const float* __restrict__ lng, const float* __restrict__ lnb,
    const float* __restrict__ wpool, const float* __restrict__ bpool,
    float* __restrict__ es)
{
  __shared__ float2 buf[256];               // 64 entries per wave
  const int t = threadIdx.x;
  const int lane = t & 63;
  const int woff = t & 192;
  const int n = (blockIdx.x * 256 + t) >> 6;
  const int row0 = __builtin_amdgcn_readfirstlane(rowptr[n]);
  const int row1 = __builtin_amdgcn_readfirstlane(rowptr[n + 1]);
  const float adn = ad2[n];
  const float eself = __expf(lrelu(as2[n] + adn));   // self-loop
  const unsigned short* __restrict__ hrow = h2b + lane;
  float a0 = eself * bf2f(hrow[(unsigned)n << 6]);
  float a1 = 0.f, a2 = 0.f, a3 = 0.f;
  float den_p = 0.f;
  for (int base = row0; base < row1; base += 64){
    const int cnt = min(64, row1 - base);
    int s = 0; float e = 0.f;
    if (lane < cnt){
      s = csr_src[base + lane];
      e = __expf(lrelu(as2[s] + adn));
    }
    den_p += e;
    buf[woff + lane] = make_float2(e, __int_as_float(s));
    int j = 0;
    for (; j + 4 <= cnt; j += 4){
      float2 p0 = buf[woff + j];
      float2 p1 = buf[woff + j + 1];
      float2 p2 = buf[woff + j + 2];
      float2 p3 = buf[woff + j + 3];
      float v0 = bf2f(hrow[(unsigned)__float_as_int(p0.y) << 6]);
      float v1 = bf2f(hrow[(unsigned)__float_as_int(p1.y) << 6]);
      float v2 = bf2f(hrow[(unsigned)__float_as_int(p2.y) << 6]);
      float v3 = bf2f(hrow[(unsigned)__float_as_int(p3.y) << 6]);
      a0 = fmaf(v0, p0.x, a0);
      a1 = fmaf(v1, p1.x, a1);
      a2 = fmaf(v2, p2.x, a2);
      a3 = fmaf(v3, p3.x, a3);
    }
    for (; j < cnt; ++j){
      float2 p0 = buf[woff + j];
      a0 = fmaf(bf2f(hrow[(unsigned)__float_as_int(p0.y) << 6]), p0.x, a0);
    }
  }
  float acc = (a0 + a1) + (a2 + a3);
  float den = wsum64(den_p) + eself;
  const size_t idxn = ((size_t)n << 6) | lane;
  float tv = acc / (den + 1e-16f) + b2[lane] + hb[idxn];
  float mu  = wsum64(tv) * (1.f / 64.f);
  float dv  = tv - mu;
  float var = wsum64(dv * dv) * (1.f / 64.f);
  float hv = dv * (1.f / sqrtf(var + 1e-5f)) * lng[lane] + lnb[lane];
  hv = eluf(hv);
  hb[idxn] = hv;
  float sl = wsum64(hv * wpool[lane]) + bpool[0];
  if (lane == 0) es[n] = __expf(sl);   // global softmax: max-shift dropped
}

// pool (UNNORMALIZED; also accumulates S = sum es). k_head scales by 1/S.
__global__ __launch_bounds__(256) void k_pool(const float* __restrict__ hf,
    const float* __restrict__ es, const int* __restrict__ batch,
    float* __restrict__ S, float* __restrict__ pooled)
{
  const int lane = threadIdx.x & 63;
  const int wseg = blockIdx.x * 4 + (threadIdx.x >> 6);
  const int base = wseg * 64;
  if (base >= NN) return;
  int end = base + 64; if (end > NN) end = NN;
  float acc = 0.f, sp = 0.f;
  int gprev = batch[base];
  for (int n = base; n < end; ++n){
    int g = batch[n];
    if (g != gprev){
      atomicAdd(&pooled[gprev * HID + lane], acc);
      acc = 0.f; gprev = g;
    }
    float e = es[n];
    sp += e;
    acc = fmaf(hf[(size_t)n * HID + lane], e, acc);
  }
  atomicAdd(&pooled[gprev * HID + lane], acc);
  if (lane == 0) atomicAdd(S, sp);
}

__global__ __launch_bounds__(64) void k_head(const float* __restrict__ pooled,
    const float* __restrict__ S, const float* __restrict__ wfc1,
    const float* __restrict__ bfc1, const float* __restrict__ wfc2,
    const float* __restrict__ bfc2, float* __restrict__ out)
{
  const int g = blockIdx.x, j = threadIdx.x;
  const float invS = 1.f / S[0];
  const float* pr = pooled + g * HID;
  float acc = 0.f;
  #pragma unroll 4
  for (int k = 0; k < HID; ++k) acc = fmaf(pr[k], wfc1[k * HID + j], acc);
  float z = eluf(acc * invS + bfc1[j]);
  float r = wsum64(z * wfc2[j]);
  if (j == 0) out[g] = r + bfc2[0];
}

extern "C" void kernel_launch(void* const* d_in, const int* in_sizes, int n_in,
                              void* d_out, int out_size, void* d_ws, size_t ws_size,
                              hipStream_t stream)
{
  const float* x     = (const float*)d_in[0];
  const int*   ei    = (const int*)d_in[1];
  const int*   batch = (const int*)d_in[2];
  const float* W1    = (const float*)d_in[4];
  const float* asw1  = (const float*)d_in[5];
  const float* adw1  = (const float*)d_in[6];
  const float* b1    = (const float*)d_in[7];
  const float* W2    = (const float*)d_in[8];
  const float* asw2  = (const float*)d_in[9];
  const float* adw2  = (const float*)d_in[10];
  const float* b2    = (const float*)d_in[11];
  const float* lng   = (const float*)d_in[12];
  const float* lnb   = (const float*)d_in[13];
  const float* wpool = (const float*)d_in[14];
  const float* bpool = (const float*)d_in[15];
  const float* wfc1  = (const float*)d_in[16];
  const float* bfc1  = (const float*)d_in[17];
  const float* wfc2  = (const float*)d_in[18];
  const float* bfc2  = (const float*)d_in[19];

  float* ws = (float*)d_ws;
  float* hb     = ws;               // NN*64 fp32: conv1 out -> residual -> hf
  float* as1    = ws +  6400000;    // NN*4
  float* ad1    = ws +  6800000;    // NN*4
  float* as2    = ws +  7200000;    // NN
  float* ad2    = ws +  7300000;    // NN
  float* es     = ws +  7400000;    // NN
  float* pooled = ws +  7500000;    // 64*64
  float* Ssum   = ws +  7504096;    // 1
  unsigned short* h1b = (unsigned short*)(ws +  7504100);  // NN*64 bf16
  unsigned short* h2b = (unsigned short*)(ws + 10704100);  // NN*64 bf16
  int* iw       = (int*)(ws + 13904100);
  int* rowptr   = iw;               // NN+1 (pad 100004)
  int* cursor   = iw + 100004;      // NN (pad 200008)
  int* deg      = iw + 200008;      // NN
  int* bsum     = iw + 300008;      // 512
  int* boff     = iw + 300520;      // 512
  int* csr_src  = iw + 301032;      // NE
  // total ~15.8M words = 63.2 MB of d_ws

  hipMemsetAsync(deg, 0, (size_t)NN * 4, stream);
  hipMemsetAsync(pooled, 0, (size_t)NGR * 64 * 4, stream);
  hipMemsetAsync(Ssum, 0, 4, stream);

  // CSR build (self-loops excluded; handled analytically in conv epilogues)
  k_deg    <<<2048, 256, 0, stream>>>(ei + NE, deg);
  k_scanA  <<<NB_SCAN, 256, 0, stream>>>(deg, rowptr, bsum);
  k_scanB  <<<1, 512, 0, stream>>>(bsum, boff);
  k_scanC  <<<NB_SCAN, 256, 0, stream>>>(rowptr, boff, cursor);
  k_scatter<<<2048, 256, 0, stream>>>(ei, cursor, csr_src);

  k_gemm1<<<6250, 256, 0, stream>>>(x, W1, asw1, adw1, h1b, as1, ad1);
  k_conv1<<<25000, 256, 0, stream>>>(rowptr, csr_src, as1, ad1, h1b, b1, hb);
  k_gemm2<<<6250, 256, 0, stream>>>(hb, W2, asw2, adw2, h2b, as2, ad2);
  k_conv2<<<25000, 256, 0, stream>>>(rowptr, csr_src, as2, ad2, h2b, b2, hb,
                                     lng, lnb, wpool, bpool, es);
  k_pool <<<391, 256, 0, stream>>>(hb, es, batch, Ssum, pooled);
  k_head <<<64, 64, 0, stream>>>(pooled, Ssum, wfc1, bfc1, wfc2, bfc2,
                                 (float*)d_out);
}

// Round 12
// 416.148 us; speedup vs baseline: 1.0389x; 1.0389x over previous
//
#include <hip/hip_runtime.h>
#include <math.h>

#define NN 100000
#define NE 1600000      // edges WITHOUT self-loops; self-loop handled analytically
#define ICH 128
#define HID 64
#define NGR 64
#define NB_SCAN 391     // ceil(100000/256)

__device__ __forceinline__ float lrelu(float x){ return x > 0.f ? x : 0.2f*x; }
__device__ __forceinline__ float eluf(float x){ return x > 0.f ? x : expm1f(x); }

__device__ __forceinline__ float bf2f(unsigned short u){
  return __uint_as_float(((unsigned int)u) << 16);
}
__device__ __forceinline__ unsigned short f2bf(float f){   // RNE
  unsigned int u = __float_as_uint(f);
  return (unsigned short)((u + 0x7FFF + ((u >> 16) & 1)) >> 16);
}

__device__ __forceinline__ float wsum64(float v){
  #pragma unroll
  for (int m = 32; m >= 1; m >>= 1) v += __shfl_xor(v, m);
  return v;
}
__device__ __forceinline__ float wsum16(float v){
  v += __shfl_xor(v, 8); v += __shfl_xor(v, 4);
  v += __shfl_xor(v, 2); v += __shfl_xor(v, 1);
  return v;
}
__device__ __forceinline__ int wscan_incl(int v){
  const int lane = threadIdx.x & 63;
  #pragma unroll
  for (int d = 1; d < 64; d <<= 1){
    int t = __shfl_up(v, d);
    if (lane >= d) v += t;
  }
  return v;
}

// ---------------- CSR build ----------------
// deg: 4 dst-windows (r8 config; hot set per window cache-local).
__global__ __launch_bounds__(256) void k_deg(const int* __restrict__ ei_dst,
                                             int* __restrict__ deg)
{
  const int lo = (blockIdx.x & 3) * 25000, hi = lo + 25000;
  const int nb = gridDim.x >> 2, ib = blockIdx.x >> 2;
  for (int e = ib * 256 + threadIdx.x; e < NE; e += nb * 256){
    int d = ei_dst[e];
    if (d >= lo && d < hi) atomicAdd(&deg[d], 1);
  }
}

__global__ __launch_bounds__(256) void k_scanA(const int* __restrict__ deg,
    int* __restrict__ rowptr, int* __restrict__ bsum)
{
  int i = blockIdx.x * 256 + threadIdx.x;
  int v = (i < NN) ? deg[i] : 0;
  int incl = wscan_incl(v);
  __shared__ int wsums[4];
  int w = threadIdx.x >> 6, lane = threadIdx.x & 63;
  if (lane == 63) wsums[w] = incl;
  __syncthreads();
  int off = 0;
  for (int k = 0; k < w; ++k) off += wsums[k];
  if (i < NN) rowptr[i] = incl - v + off;
  if (threadIdx.x == 255) bsum[blockIdx.x] = off + incl;
}

__global__ __launch_bounds__(512) void k_scanB(const int* __restrict__ bsum,
                                               int* __restrict__ boff)
{
  int i = threadIdx.x;
  int v = (i < NB_SCAN) ? bsum[i] : 0;
  int incl = wscan_incl(v);
  __shared__ int wsums[8];
  int w = threadIdx.x >> 6, lane = threadIdx.x & 63;
  if (lane == 63) wsums[w] = incl;
  __syncthreads();
  int off = 0;
  for (int k = 0; k < w; ++k) off += wsums[k];
  if (i < NB_SCAN) boff[i] = incl - v + off;
}

__global__ __launch_bounds__(256) void k_scanC(int* __restrict__ rowptr,
    const int* __restrict__ boff, int* __restrict__ cursor)
{
  int i = blockIdx.x * 256 + threadIdx.x;
  if (i < NN){
    int val = rowptr[i] + boff[blockIdx.x];
    rowptr[i] = val;
    cursor[i] = val;
  }
  if (i == 0) rowptr[NN] = NE;
}

// scatter: 8 dst-windows -> target region ~800KB stays in one XCD's L2.
__global__ __launch_bounds__(256) void k_scatter(const int* __restrict__ ei,
    int* __restrict__ cursor, int* __restrict__ csr_src)
{
  const int lo = (blockIdx.x & 7) * 12500, hi = lo + 12500;
  const int nb = gridDim.x >> 3, ib = blockIdx.x >> 3;
  for (int e = ib * 256 + threadIdx.x; e < NE; e += nb * 256){
    int d = ei[NE + e];
    if (d >= lo && d < hi){
      int pos = atomicAdd(&cursor[d], 1);
      csr_src[pos] = ei[e];
    }
  }
}

// ---------------- dense node kernels ----------------
// h1 = x @ W1 + per-head attention logits. x tile in LDS; W1 via global
// (32KB, L1-resident — r11 measured that LDS-staging W1 REGRESSES: occupancy
// drop + 200MB of per-block staging traffic).
__global__ __launch_bounds__(256) void k_gemm1(const float* __restrict__ x,
    const float* __restrict__ W1, const float* __restrict__ asw,
    const float* __restrict__ adw, unsigned short* __restrict__ h1b,
    float* __restrict__ as1, float* __restrict__ ad1)
{
  __shared__ float xs[16 * ICH];            // 8 KB
  const int t = threadIdx.x;
  const int n0 = blockIdx.x * 16;
  const float4* xg4 = (const float4*)(x + (size_t)n0 * ICH);
  float4* xs4 = (float4*)xs;
  xs4[t]       = xg4[t];
  xs4[t + 256] = xg4[t + 256];
  __syncthreads();

  const int lane = t & 63;
  const float* xr = xs + (t >> 6) * 4 * ICH;   // wave's 4 rows
  float a0 = 0.f, a1 = 0.f, a2 = 0.f, a3 = 0.f;
  #pragma unroll 8
  for (int k = 0; k < ICH; ++k){
    const float w = W1[k * HID + lane];
    a0 = fmaf(xr[k],          w, a0);
    a1 = fmaf(xr[ICH + k],    w, a1);
    a2 = fmaf(xr[2*ICH + k],  w, a2);
    a3 = fmaf(xr[3*ICH + k],  w, a3);
  }
  const float sw = asw[lane], dw = adw[lane];  // att layout [H][16] flattens to [64]
  const int nw = n0 + (t >> 6) * 4;
  float acc[4] = {a0, a1, a2, a3};
  #pragma unroll
  for (int i = 0; i < 4; ++i){
    const int n = nw + i;
    h1b[(size_t)n * HID + lane] = f2bf(acc[i]);
    float ps = wsum16(acc[i] * sw);
    float pd = wsum16(acc[i] * dw);
    if ((lane & 15) == 0){
      as1[n * 4 + (lane >> 4)] = ps;
      ad1[n * 4 + (lane >> 4)] = pd;
    }
  }
}

// conv1 (r8 best): batched edges (16/batch x 4 heads), LDS {e,s} park,
// 4x-unrolled broadcast loop, self-loop analytic, normalize after sum.
__global__ __launch_bounds__(256) void k_conv1(const int* __restrict__ rowptr,
    const int* __restrict__ csr_src, const float* __restrict__ as1,
    const float* __restrict__ ad1, const unsigned short* __restrict__ h1b,
    const float* __restrict__ b1, float* __restrict__ hb)
{
  __shared__ float2 buf[256];               // 64 entries per wave
  const int t = threadIdx.x;
  const int lane = t & 63;
  const int h = lane >> 4;                  // head
  const int m = lane & 15;                  // edge slot within batch
  const int woff = t & 192;                 // wave's LDS window base
  const int n = (blockIdx.x * 256 + t) >> 6;
  const int row0 = __builtin_amdgcn_readfirstlane(rowptr[n]);
  const int row1 = __builtin_amdgcn_readfirstlane(rowptr[n + 1]);
  const float adh = ad1[4 * n + h];
  const float eself = __expf(lrelu(as1[4 * n + h] + adh));   // self-loop
  const unsigned short* __restrict__ hrow = h1b + lane;
  float a0 = eself * bf2f(hrow[(unsigned)n << 6]);
  float a1 = 0.f, a2 = 0.f, a3 = 0.f;
  float den_p = 0.f;
  const int rbase = woff + (lane & 48);     // = woff + h*16
  for (int base = row0; base < row1; base += 16){
    const int cnt = min(16, row1 - base);
    int s = 0; float e = 0.f;
    if (m < cnt){
      s = csr_src[base + m];
      e = __expf(lrelu(as1[4 * s + h] + adh));
    }
    den_p += e;
    buf[woff + lane] = make_float2(e, __int_as_float(s));
    // same-wave RAW: compiler orders via lgkmcnt; buffer is wave-private.
    int j = 0;
    for (; j + 4 <= cnt; j += 4){
      float2 p0 = buf[rbase + j];
      float2 p1 = buf[rbase + j + 1];
      float2 p2 = buf[rbase + j + 2];
      float2 p3 = buf[rbase + j + 3];
      float v0 = bf2f(hrow[(unsigned)__float_as_int(p0.y) << 6]);
      float v1 = bf2f(hrow[(unsigned)__float_as_int(p1.y) << 6]);
      float v2 = bf2f(hrow[(unsigned)__float_as_int(p2.y) << 6]);
      float v3 = bf2f(hrow[(unsigned)__float_as_int(p3.y) << 6]);
      a0 = fmaf(v0, p0.x, a0);
      a1 = fmaf(v1, p1.x, a1);
      a2 = fmaf(v2, p2.x, a2);
      a3 = fmaf(v3, p3.x, a3);
    }
    for (; j < cnt; ++j){
      float2 p0 = buf[rbase + j];
      a0 = fmaf(bf2f(hrow[(unsigned)__float_as_int(p0.y) << 6]), p0.x, a0);
    }
  }
  float acc = (a0 + a1) + (a2 + a3);
  float den = wsum16(den_p) + eself;
  float o = acc / (den + 1e-16f) + b1[lane];
  hb[((size_t)n << 6) | lane] = eluf(o);
}

// h2 = h @ W2 (64x64) + scalar-head attention logits; h tile in LDS,
// W2 via global/L1 (r8 form — W2-in-LDS regressed in r11).
__global__ __launch_bounds__(256) void k_gemm2(const float* __restrict__ h,
    const float* __restrict__ W2, const float* __restrict__ asw,
    const float* __restrict__ adw, unsigned short* __restrict__ h2b,
    float* __restrict__ as2, float* __restrict__ ad2)
{
  __shared__ float hs[16 * HID];            // 4 KB
  const int t = threadIdx.x;
  const int n0 = blockIdx.x * 16;
  const float4* hg4 = (const float4*)(h + (size_t)n0 * HID);
  float4* hs4 = (float4*)hs;
  hs4[t] = hg4[t];
  __syncthreads();

  const int lane = t & 63;
  const float* hr = hs + (t >> 6) * 4 * HID;
  float a0 = 0.f, a1 = 0.f, a2 = 0.f, a3 = 0.f;
  #pragma unroll 8
  for (int k = 0; k < HID; ++k){
    const float w = W2[k * HID + lane];
    a0 = fmaf(hr[k],          w, a0);
    a1 = fmaf(hr[HID + k],    w, a1);
    a2 = fmaf(hr[2*HID + k],  w, a2);
    a3 = fmaf(hr[3*HID + k],  w, a3);
  }
  const float sw = asw[lane], dw = adw[lane];
  const int nw = n0 + (t >> 6) * 4;
  float acc[4] = {a0, a1, a2, a3};
  #pragma unroll
  for (int i = 0; i < 4; ++i){
    const int n = nw + i;
    h2b[(size_t)n * HID + lane] = f2bf(acc[i]);
    float ps = wsum64(acc[i] * sw);
    float pd = wsum64(acc[i] * dw);
    if (lane == 0){ as2[n] = ps; ad2[n] = pd; }
  }
}

// conv2 (r8 best): batched edges (64/batch) + 4x unroll + fused residual +
// LayerNorm + elu + pool logit. hf aliases hb (own-row RAW only).
__global__ __launch_bounds__(256) void k_conv2(const int* __restrict__ rowptr,
    const int* __restrict__ csr_src, const float* __restrict__ as2,
    const float* __restrict__ ad2, const unsigned short* __restrict__ h2b,
    const float* __restrict__ b2, float* __restrict__ hb,
    const float* __restrict__ lng, const float* __restrict__ lnb,
    const float* __restrict__ wpool, const float* __restrict__ bpool,
    float* __restrict__ es)
{
  __shared__ float2 buf[256];               // 64 entries per wave
  const int t = threadIdx.x;
  const int lane = t & 63;
  const int woff = t & 192;
  const int n = (blockIdx.x * 256 + t) >> 6;
  const int row0 = __builtin_amdgcn_readfirstlane(rowptr[n]);
  const int row1 = __builtin_amdgcn_readfirstlane(rowptr[n + 1]);
  const float adn = ad2[n];
  const float eself = __expf(lrelu(as2[n] + adn));   // self-loop
  const unsigned short* __restrict__ hrow = h2b + lane;
  float a0 = eself * bf2f(hrow[(unsigned)n << 6]);
  float a1 = 0.f, a2 = 0.f, a3 = 0.f;
  float den_p = 0.f;
  for (int base = row0; base < row1; base += 64){
    const int cnt = min(64, row1 - base);
    int s = 0; float e = 0.f;
    if (lane < cnt){
      s = csr_src[base + lane];
      e = __expf(lrelu(as2[s] + adn));
    }
    den_p += e;
    buf[woff + lane] = make_float2(e, __int_as_float(s));
    int j = 0;
    for (; j + 4 <= cnt; j += 4){
      float2 p0 = buf[woff + j];
      float2 p1 = buf[woff + j + 1];
      float2 p2 = buf[woff + j + 2];
      float2 p3 = buf[woff + j + 3];
      float v0 = bf2f(hrow[(unsigned)__float_as_int(p0.y) << 6]);
      float v1 = bf2f(hrow[(unsigned)__float_as_int(p1.y) << 6]);
      float v2 = bf2f(hrow[(unsigned)__float_as_int(p2.y) << 6]);
      float v3 = bf2f(hrow[(unsigned)__float_as_int(p3.y) << 6]);
      a0 = fmaf(v0, p0.x, a0);
      a1 = fmaf(v1, p1.x, a1);
      a2 = fmaf(v2, p2.x, a2);
      a3 = fmaf(v3, p3.x, a3);
    }
    for (; j < cnt; ++j){
      float2 p0 = buf[woff + j];
      a0 = fmaf(bf2f(hrow[(unsigned)__float_as_int(p0.y) << 6]), p0.x, a0);
    }
  }
  float acc = (a0 + a1) + (a2 + a3);
  float den = wsum64(den_p) + eself;
  const size_t idxn = ((size_t)n << 6) | lane;
  float tv = acc / (den + 1e-16f) + b2[lane] + hb[idxn];
  float mu  = wsum64(tv) * (1.f / 64.f);
  float dv  = tv - mu;
  float var = wsum64(dv * dv) * (1.f / 64.f);
  float hv = dv * (1.f / sqrtf(var + 1e-5f)) * lng[lane] + lnb[lane];
  hv = eluf(hv);
  hb[idxn] = hv;
  float sl = wsum64(hv * wpool[lane]) + bpool[0];
  if (lane == 0) es[n] = __expf(sl);   // global softmax: max-shift dropped
}

// pool (UNNORMALIZED; also accumulates S = sum es). k_head scales by 1/S —
// exact by linearity of pooled@wfc1.
__global__ __launch_bounds__(256) void k_pool(const float* __restrict__ hf,
    const float* __restrict__ es, const int* __restrict__ batch,
    float* __restrict__ S, float* __restrict__ pooled)
{
  const int lane = threadIdx.x & 63;
  const int wseg = blockIdx.x * 4 + (threadIdx.x >> 6);
  const int base = wseg * 64;
  if (base >= NN) return;
  int end = base + 64; if (end > NN) end = NN;
  float acc = 0.f, sp = 0.f;
  int gprev = batch[base];
  for (int n = base; n < end; ++n){
    int g = batch[n];
    if (g != gprev){
      atomicAdd(&pooled[gprev * HID + lane], acc);
      acc = 0.f; gprev = g;
    }
    float e = es[n];
    sp += e;
    acc = fmaf(hf[(size_t)n * HID + lane], e, acc);
  }
  atomicAdd(&pooled[gprev * HID + lane], acc);
  if (lane == 0) atomicAdd(S, sp);
}

__global__ __launch_bounds__(64) void k_head(const float* __restrict__ pooled,
    const float* __restrict__ S, const float* __restrict__ wfc1,
    const float* __restrict__ bfc1, const float* __restrict__ wfc2,
    const float* __restrict__ bfc2, float* __restrict__ out)
{
  const int g = blockIdx.x, j = threadIdx.x;
  const float invS = 1.f / S[0];
  const float* pr = pooled + g * HID;
  float acc = 0.f;
  #pragma unroll 4
  for (int k = 0; k < HID; ++k) acc = fmaf(pr[k], wfc1[k * HID + j], acc);
  float z = eluf(acc * invS + bfc1[j]);
  float r = wsum64(z * wfc2[j]);
  if (j == 0) out[g] = r + bfc2[0];
}

extern "C" void kernel_launch(void* const* d_in, const int* in_sizes, int n_in,
                              void* d_out, int out_size, void* d_ws, size_t ws_size,
                              hipStream_t stream)
{
  const float* x     = (const float*)d_in[0];
  const int*   ei    = (const int*)d_in[1];
  const int*   batch = (const int*)d_in[2];
  const float* W1    = (const float*)d_in[4];
  const float* asw1  = (const float*)d_in[5];
  const float* adw1  = (const float*)d_in[6];
  const float* b1    = (const float*)d_in[7];
  const float* W2    = (const float*)d_in[8];
  const float* asw2  = (const float*)d_in[9];
  const float* adw2  = (const float*)d_in[10];
  const float* b2    = (const float*)d_in[11];
  const float* lng   = (const float*)d_in[12];
  const float* lnb   = (const float*)d_in[13];
  const float* wpool = (const float*)d_in[14];
  const float* bpool = (const float*)d_in[15];
  const float* wfc1  = (const float*)d_in[16];
  const float* bfc1  = (const float*)d_in[17];
  const float* wfc2  = (const float*)d_in[18];
  const float* bfc2  = (const float*)d_in[19];

  float* ws = (float*)d_ws;
  float* hb     = ws;               // NN*64 fp32: conv1 out -> residual -> hf
  float* as1    = ws +  6400000;    // NN*4
  float* ad1    = ws +  6800000;    // NN*4
  float* as2    = ws +  7200000;    // NN
  float* ad2    = ws +  7300000;    // NN
  float* es     = ws +  7400000;    // NN
  float* pooled = ws +  7500000;    // 64*64
  float* Ssum   = ws +  7504096;    // 1
  unsigned short* h1b = (unsigned short*)(ws +  7504100);  // NN*64 bf16
  unsigned short* h2b = (unsigned short*)(ws + 10704100);  // NN*64 bf16
  int* iw       = (int*)(ws + 13904100);
  int* rowptr   = iw;               // NN+1 (pad 100004)
  int* cursor   = iw + 100004;      // NN (pad 200008)
  int* deg      = iw + 200008;      // NN
  int* bsum     = iw + 300008;      // 512
  int* boff     = iw + 300520;      // 512
  int* csr_src  = iw + 301032;      // NE
  // total ~15.8M words = 63.2 MB of d_ws

  hipMemsetAsync(deg, 0, (size_t)NN * 4, stream);
  hipMemsetAsync(pooled, 0, (size_t)NGR * 64 * 4, stream);
  hipMemsetAsync(Ssum, 0, 4, stream);

  // CSR build (self-loops excluded; handled analytically in conv epilogues)
  k_deg    <<<2048, 256, 0, stream>>>(ei + NE, deg);
  k_scanA  <<<NB_SCAN, 256, 0, stream>>>(deg, rowptr, bsum);
  k_scanB  <<<1, 512, 0, stream>>>(bsum, boff);
  k_scanC  <<<NB_SCAN, 256, 0, stream>>>(rowptr, boff, cursor);
  k_scatter<<<2048, 256, 0, stream>>>(ei, cursor, csr_src);

  k_gemm1<<<6250, 256, 0, stream>>>(x, W1, asw1, adw1, h1b, as1, ad1);
  k_conv1<<<25000, 256, 0, stream>>>(rowptr, csr_src, as1, ad1, h1b, b1, hb);
  k_gemm2<<<6250, 256, 0, stream>>>(hb, W2, asw2, adw2, h2b, as2, ad2);
  k_conv2<<<25000, 256, 0, stream>>>(rowptr, csr_src, as2, ad2, h2b, b2, hb,
                                     lng, lnb, wpool, bpool, es);
  k_pool <<<391, 256, 0, stream>>>(hb, es, batch, Ssum, pooled);
  k_head <<<64, 64, 0, stream>>>(pooled, Ssum, wfc1, bfc1, wfc2, bfc2,
                                 (float*)d_out);
}

// Round 13
// 410.325 us; speedup vs baseline: 1.0536x; 1.0142x over previous
//
#include <hip/hip_runtime.h>
#include <math.h>

#define NN 100000
#define NE 1600000      // edges WITHOUT self-loops; self-loop handled analytically
#define ICH 128
#define HID 64
#define NGR 64
#define NB_SCAN 391     // ceil(100000/256)

__device__ __forceinline__ float lrelu(float x){ return x > 0.f ? x : 0.2f*x; }
__device__ __forceinline__ float eluf(float x){ return x > 0.f ? x : expm1f(x); }

__device__ __forceinline__ float bf2f(unsigned short u){
  return __uint_as_float(((unsigned int)u) << 16);
}
__device__ __forceinline__ unsigned short f2bf(float f){   // RNE
  unsigned int u = __float_as_uint(f);
  return (unsigned short)((u + 0x7FFF + ((u >> 16) & 1)) >> 16);
}

__device__ __forceinline__ float wsum64(float v){
  #pragma unroll
  for (int m = 32; m >= 1; m >>= 1) v += __shfl_xor(v, m);
  return v;
}
__device__ __forceinline__ float wsum16(float v){
  v += __shfl_xor(v, 8); v += __shfl_xor(v, 4);
  v += __shfl_xor(v, 2); v += __shfl_xor(v, 1);
  return v;
}
__device__ __forceinline__ int wscan_incl(int v){
  const int lane = threadIdx.x & 63;
  #pragma unroll
  for (int d = 1; d < 64; d <<= 1){
    int t = __shfl_up(v, d);
    if (lane >= d) v += t;
  }
  return v;
}

// ---------------- CSR build ----------------
// deg: 4 dst-windows (r8 measured-good config).
__global__ __launch_bounds__(256) void k_deg(const int* __restrict__ ei_dst,
                                             int* __restrict__ deg)
{
  const int lo = (blockIdx.x & 3) * 25000, hi = lo + 25000;
  const int nb = gridDim.x >> 2, ib = blockIdx.x >> 2;
  for (int e = ib * 256 + threadIdx.x; e < NE; e += nb * 256){
    int d = ei_dst[e];
    if (d >= lo && d < hi) atomicAdd(&deg[d], 1);
  }
}

__global__ __launch_bounds__(256) void k_scanA(const int* __restrict__ deg,
    int* __restrict__ rowptr, int* __restrict__ bsum)
{
  int i = blockIdx.x * 256 + threadIdx.x;
  int v = (i < NN) ? deg[i] : 0;
  int incl = wscan_incl(v);
  __shared__ int wsums[4];
  int w = threadIdx.x >> 6, lane = threadIdx.x & 63;
  if (lane == 63) wsums[w] = incl;
  __syncthreads();
  int off = 0;
  for (int k = 0; k < w; ++k) off += wsums[k];
  if (i < NN) rowptr[i] = incl - v + off;
  if (threadIdx.x == 255) bsum[blockIdx.x] = off + incl;
}

__global__ __launch_bounds__(512) void k_scanB(const int* __restrict__ bsum,
                                               int* __restrict__ boff)
{
  int i = threadIdx.x;
  int v = (i < NB_SCAN) ? bsum[i] : 0;
  int incl = wscan_incl(v);
  __shared__ int wsums[8];
  int w = threadIdx.x >> 6, lane = threadIdx.x & 63;
  if (lane == 63) wsums[w] = incl;
  __syncthreads();
  int off = 0;
  for (int k = 0; k < w; ++k) off += wsums[k];
  if (i < NB_SCAN) boff[i] = incl - v + off;
}

__global__ __launch_bounds__(256) void k_scanC(int* __restrict__ rowptr,
    const int* __restrict__ boff, int* __restrict__ cursor)
{
  int i = blockIdx.x * 256 + threadIdx.x;
  if (i < NN){
    int val = rowptr[i] + boff[blockIdx.x];
    rowptr[i] = val;
    cursor[i] = val;
  }
  if (i == 0) rowptr[NN] = NE;
}

// scatter: 4 dst-windows (halved redundant dst re-read vs 8; per-window
// target region ~1.6MB still L2-resident, cursor slice window-exclusive).
__global__ __launch_bounds__(256) void k_scatter(const int* __restrict__ ei,
    int* __restrict__ cursor, int* __restrict__ csr_src)
{
  const int lo = (blockIdx.x & 3) * 25000, hi = lo + 25000;
  const int nb = gridDim.x >> 2, ib = blockIdx.x >> 2;
  for (int e = ib * 256 + threadIdx.x; e < NE; e += nb * 256){
    int d = ei[NE + e];
    if (d >= lo && d < hi){
      int pos = atomicAdd(&cursor[d], 1);
      csr_src[pos] = ei[e];
    }
  }
}

// ---------------- dense node kernels ----------------
// h1 = x @ W1 + per-head attention logits. x tile in LDS; W1 via global
// (32KB, L1-resident — r11 measured that LDS-staging W1 REGRESSES).
__global__ __launch_bounds__(256) void k_gemm1(const float* __restrict__ x,
    const float* __restrict__ W1, const float* __restrict__ asw,
    const float* __restrict__ adw, unsigned short* __restrict__ h1b,
    float* __restrict__ as1, float* __restrict__ ad1)
{
  __shared__ float xs[16 * ICH];            // 8 KB
  const int t = threadIdx.x;
  const int n0 = blockIdx.x * 16;
  const float4* xg4 = (const float4*)(x + (size_t)n0 * ICH);
  float4* xs4 = (float4*)xs;
  xs4[t]       = xg4[t];
  xs4[t + 256] = xg4[t + 256];
  __syncthreads();

  const int lane = t & 63;
  const float* xr = xs + (t >> 6) * 4 * ICH;   // wave's 4 rows
  float a0 = 0.f, a1 = 0.f, a2 = 0.f, a3 = 0.f;
  #pragma unroll 8
  for (int k = 0; k < ICH; ++k){
    const float w = W1[k * HID + lane];
    a0 = fmaf(xr[k],          w, a0);
    a1 = fmaf(xr[ICH + k],    w, a1);
    a2 = fmaf(xr[2*ICH + k],  w, a2);
    a3 = fmaf(xr[3*ICH + k],  w, a3);
  }
  const float sw = asw[lane], dw = adw[lane];  // att layout [H][16] flattens to [64]
  const int nw = n0 + (t >> 6) * 4;
  float acc[4] = {a0, a1, a2, a3};
  #pragma unroll
  for (int i = 0; i < 4; ++i){
    const int n = nw + i;
    h1b[(size_t)n * HID + lane] = f2bf(acc[i]);
    float ps = wsum16(acc[i] * sw);
    float pd = wsum16(acc[i] * dw);
    if ((lane & 15) == 0){
      as1[n * 4 + (lane >> 4)] = ps;
      ad1[n * 4 + (lane >> 4)] = pd;
    }
  }
}

// conv1 (r8 best): batched edges (16/batch x 4 heads), LDS {e,s} park,
// 4x-unrolled broadcast loop, self-loop analytic, normalize after sum.
__global__ __launch_bounds__(256) void k_conv1(const int* __restrict__ rowptr,
    const int* __restrict__ csr_src, const float* __restrict__ as1,
    const float* __restrict__ ad1, const unsigned short* __restrict__ h1b,
    const float* __restrict__ b1, float* __restrict__ hb)
{
  __shared__ float2 buf[256];               // 64 entries per wave
  const int t = threadIdx.x;
  const int lane = t & 63;
  const int h = lane >> 4;                  // head
  const int m = lane & 15;                  // edge slot within batch
  const int woff = t & 192;                 // wave's LDS window base
  const int n = (blockIdx.x * 256 + t) >> 6;
  const int row0 = __builtin_amdgcn_readfirstlane(rowptr[n]);
  const int row1 = __builtin_amdgcn_readfirstlane(rowptr[n + 1]);
  const float adh = ad1[4 * n + h];
  const float eself = __expf(lrelu(as1[4 * n + h] + adh));   // self-loop
  const unsigned short* __restrict__ hrow = h1b + lane;
  float a0 = eself * bf2f(hrow[(unsigned)n << 6]);
  float a1 = 0.f, a2 = 0.f, a3 = 0.f;
  float den_p = 0.f;
  const int rbase = woff + (lane & 48);     // = woff + h*16
  for (int base = row0; base < row1; base += 16){
    const int cnt = min(16, row1 - base);
    int s = 0; float e = 0.f;
    if (m < cnt){
      s = csr_src[base + m];
      e = __expf(lrelu(as1[4 * s + h] + adh));
    }
    den_p += e;
    buf[woff + lane] = make_float2(e, __int_as_float(s));
    // same-wave RAW: compiler orders via lgkmcnt; buffer is wave-private.
    int j = 0;
    for (; j + 4 <= cnt; j += 4){
      float2 p0 = buf[rbase + j];
      float2 p1 = buf[rbase + j + 1];
      float2 p2 = buf[rbase + j + 2];
      float2 p3 = buf[rbase + j + 3];
      float v0 = bf2f(hrow[(unsigned)__float_as_int(p0.y) << 6]);
      float v1 = bf2f(hrow[(unsigned)__float_as_int(p1.y) << 6]);
      float v2 = bf2f(hrow[(unsigned)__float_as_int(p2.y) << 6]);
      float v3 = bf2f(hrow[(unsigned)__float_as_int(p3.y) << 6]);
      a0 = fmaf(v0, p0.x, a0);
      a1 = fmaf(v1, p1.x, a1);
      a2 = fmaf(v2, p2.x, a2);
      a3 = fmaf(v3, p3.x, a3);
    }
    for (; j < cnt; ++j){
      float2 p0 = buf[rbase + j];
      a0 = fmaf(bf2f(hrow[(unsigned)__float_as_int(p0.y) << 6]), p0.x, a0);
    }
  }
  float acc = (a0 + a1) + (a2 + a3);
  float den = wsum16(den_p) + eself;
  float o = acc / (den + 1e-16f) + b1[lane];
  hb[((size_t)n << 6) | lane] = eluf(o);
}

// h2 = h @ W2 (64x64) + scalar-head attention logits; h tile in LDS,
// W2 via global/L1 (r8 form — W2-in-LDS regressed in r11).
__global__ __launch_bounds__(256) void k_gemm2(const float* __restrict__ h,
    const float* __restrict__ W2, const float* __restrict__ asw,
    const float* __restrict__ adw, unsigned short* __restrict__ h2b,
    float* __restrict__ as2, float* __restrict__ ad2)
{
  __shared__ float hs[16 * HID];            // 4 KB
  const int t = threadIdx.x;
  const int n0 = blockIdx.x * 16;
  const float4* hg4 = (const float4*)(h + (size_t)n0 * HID);
  float4* hs4 = (float4*)hs;
  hs4[t] = hg4[t];
  __syncthreads();

  const int lane = t & 63;
  const float* hr = hs + (t >> 6) * 4 * HID;
  float a0 = 0.f, a1 = 0.f, a2 = 0.f, a3 = 0.f;
  #pragma unroll 8
  for (int k = 0; k < HID; ++k){
    const float w = W2[k * HID + lane];
    a0 = fmaf(hr[k],          w, a0);
    a1 = fmaf(hr[HID + k],    w, a1);
    a2 = fmaf(hr[2*HID + k],  w, a2);
    a3 = fmaf(hr[3*HID + k],  w, a3);
  }
  const float sw = asw[lane], dw = adw[lane];
  const int nw = n0 + (t >> 6) * 4;
  float acc[4] = {a0, a1, a2, a3};
  #pragma unroll
  for (int i = 0; i < 4; ++i){
    const int n = nw + i;
    h2b[(size_t)n * HID + lane] = f2bf(acc[i]);
    float ps = wsum64(acc[i] * sw);
    float pd = wsum64(acc[i] * dw);
    if (lane == 0){ as2[n] = ps; ad2[n] = pd; }
  }
}

// conv2 (r8 best): batched edges (64/batch) + 4x unroll + fused residual +
// LayerNorm + elu + pool logit. hf aliases hb (own-row RAW only).
__global__ __launch_bounds__(256) void k_conv2(const int* __restrict__ rowptr,
    const int* __restrict__ csr_src, const float* __restrict__ as2,
    const float* __restrict__ ad2, const unsigned short* __restrict__ h2b,
    const float* __restrict__ b2, float* __restrict__ hb,
    const float* __restrict__ lng, const float* __restrict__ lnb,
    const float* __restrict__ wpool, const float* __restrict__ bpool,
    float* __restrict__ es)
{
  __shared__ float2 buf[256];               // 64 entries per wave
  const int t = threadIdx.x;
  const int lane = t & 63;
  const int woff = t & 192;
  const int n = (blockIdx.x * 256 + t) >> 6;
  const int row0 = __builtin_amdgcn_readfirstlane(rowptr[n]);
  const int row1 = __builtin_amdgcn_readfirstlane(rowptr[n + 1]);
  const float adn = ad2[n];
  const float eself = __expf(lrelu(as2[n] + adn));   // self-loop
  const unsigned short* __restrict__ hrow = h2b + lane;
  float a0 = eself * bf2f(hrow[(unsigned)n << 6]);
  float a1 = 0.f, a2 = 0.f, a3 = 0.f;
  float den_p = 0.f;
  for (int base = row0; base < row1; base += 64){
    const int cnt = min(64, row1 - base);
    int s = 0; float e = 0.f;
    if (lane < cnt){
      s = csr_src[base + lane];
      e = __expf(lrelu(as2[s] + adn));
    }
    den_p += e;
    buf[woff + lane] = make_float2(e, __int_as_float(s));
    int j = 0;
    for (; j + 4 <= cnt; j += 4){
      float2 p0 = buf[woff + j];
      float2 p1 = buf[woff + j + 1];
      float2 p2 = buf[woff + j + 2];
      float2 p3 = buf[woff + j + 3];
      float v0 = bf2f(hrow[(unsigned)__float_as_int(p0.y) << 6]);
      float v1 = bf2f(hrow[(unsigned)__float_as_int(p1.y) << 6]);
      float v2 = bf2f(hrow[(unsigned)__float_as_int(p2.y) << 6]);
      float v3 = bf2f(hrow[(unsigned)__float_as_int(p3.y) << 6]);
      a0 = fmaf(v0, p0.x, a0);
      a1 = fmaf(v1, p1.x, a1);
      a2 = fmaf(v2, p2.x, a2);
      a3 = fmaf(v3, p3.x, a3);
    }
    for (; j < cnt; ++j){
      float2 p0 = buf[woff + j];
      a0 = fmaf(bf2f(hrow[(unsigned)__float_as_int(p0.y) << 6]), p0.x, a0);
    }
  }
  float acc = (a0 + a1) + (a2 + a3);
  float den = wsum64(den_p) + eself;
  const size_t idxn = ((size_t)n << 6) | lane;
  float tv = acc / (den + 1e-16f) + b2[lane] + hb[idxn];
  float mu  = wsum64(tv) * (1.f / 64.f);
  float dv  = tv - mu;
  float var = wsum64(dv * dv) * (1.f / 64.f);
  float hv = dv * (1.f / sqrtf(var + 1e-5f)) * lng[lane] + lnb[lane];
  hv = eluf(hv);
  hb[idxn] = hv;
  float sl = wsum64(hv * wpool[lane]) + bpool[0];
  if (lane == 0) es[n] = __expf(sl);   // global softmax: max-shift dropped
}

// pool (UNNORMALIZED; also accumulates S = sum es). k_head scales by 1/S —
// exact by linearity of pooled@wfc1.
__global__ __launch_bounds__(256) void k_pool(const float* __restrict__ hf,
    const float* __restrict__ es, const int* __restrict__ batch,
    float* __restrict__ S, float* __restrict__ pooled)
{
  const int lane = threadIdx.x & 63;
  const int wseg = blockIdx.x * 4 + (threadIdx.x >> 6);
  const int base = wseg * 64;
  if (base >= NN) return;
  int end = base + 64; if (end > NN) end = NN;
  float acc = 0.f, sp = 0.f;
  int gprev = batch[base];
  for (int n = base; n < end; ++n){
    int g = batch[n];
    if (g != gprev){
      atomicAdd(&pooled[gprev * HID + lane], acc);
      acc = 0.f; gprev = g;
    }
    float e = es[n];
    sp += e;
    acc = fmaf(hf[(size_t)n * HID + lane], e, acc);
  }
  atomicAdd(&pooled[gprev * HID + lane], acc);
  if (lane == 0) atomicAdd(S, sp);
}

__global__ __launch_bounds__(64) void k_head(const float* __restrict__ pooled,
    const float* __restrict__ S, const float* __restrict__ wfc1,
    const float* __restrict__ bfc1, const float* __restrict__ wfc2,
    const float* __restrict__ bfc2, float* __restrict__ out)
{
  const int g = blockIdx.x, j = threadIdx.x;
  const float invS = 1.f / S[0];
  const float* pr = pooled + g * HID;
  float acc = 0.f;
  #pragma unroll 4
  for (int k = 0; k < HID; ++k) acc = fmaf(pr[k], wfc1[k * HID + j], acc);
  float z = eluf(acc * invS + bfc1[j]);
  float r = wsum64(z * wfc2[j]);
  if (j == 0) out[g] = r + bfc2[0];
}

extern "C" void kernel_launch(void* const* d_in, const int* in_sizes, int n_in,
                              void* d_out, int out_size, void* d_ws, size_t ws_size,
                              hipStream_t stream)
{
  const float* x     = (const float*)d_in[0];
  const int*   ei    = (const int*)d_in[1];
  const int*   batch = (const int*)d_in[2];
  const float* W1    = (const float*)d_in[4];
  const float* asw1  = (const float*)d_in[5];
  const float* adw1  = (const float*)d_in[6];
  const float* b1    = (const float*)d_in[7];
  const float* W2    = (const float*)d_in[8];
  const float* asw2  = (const float*)d_in[9];
  const float* adw2  = (const float*)d_in[10];
  const float* b2    = (const float*)d_in[11];
  const float* lng   = (const float*)d_in[12];
  const float* lnb   = (const float*)d_in[13];
  const float* wpool = (const float*)d_in[14];
  const float* bpool = (const float*)d_in[15];
  const float* wfc1  = (const float*)d_in[16];
  const float* bfc1  = (const float*)d_in[17];
  const float* wfc2  = (const float*)d_in[18];
  const float* bfc2  = (const float*)d_in[19];

  float* ws = (float*)d_ws;
  float* hb     = ws;               // NN*64 fp32: conv1 out -> residual -> hf
  float* as1    = ws +  6400000;    // NN*4
  float* ad1    = ws +  6800000;    // NN*4
  float* as2    = ws +  7200000;    // NN
  float* ad2    = ws +  7300000;    // NN
  float* es     = ws +  7400000;    // NN
  // --- zero-init region (single memset): pooled | Ssum | deg ---
  float* pooled = ws +  7500000;    // 64*64 = 4096
  float* Ssum   = ws +  7504096;    // 1
  int*   deg    = (int*)(ws + 7504100);   // NN
  // -------------------------------------------------------------
  unsigned short* h1b = (unsigned short*)(ws +  7604100);  // NN*64 bf16
  unsigned short* h2b = (unsigned short*)(ws + 10804100);  // NN*64 bf16
  int* iw       = (int*)(ws + 14004100);
  int* rowptr   = iw;               // NN+1 (pad 100004)
  int* cursor   = iw + 100004;      // NN (pad 200008)
  int* bsum     = iw + 200008;      // 512
  int* boff     = iw + 200520;      // 512
  int* csr_src  = iw + 201032;      // NE
  // total ~15.8M words = 63.2 MB of d_ws

  hipMemsetAsync(pooled, 0, (size_t)(4096 + 4 + NN) * 4, stream);

  // CSR build (self-loops excluded; handled analytically in conv epilogues)
  k_deg    <<<2048, 256, 0, stream>>>(ei + NE, deg);
  k_scanA  <<<NB_SCAN, 256, 0, stream>>>(deg, rowptr, bsum);
  k_scanB  <<<1, 512, 0, stream>>>(bsum, boff);
  k_scanC  <<<NB_SCAN, 256, 0, stream>>>(rowptr, boff, cursor);
  k_scatter<<<2048, 256, 0, stream>>>(ei, cursor, csr_src);

  k_gemm1<<<6250, 256, 0, stream>>>(x, W1, asw1, adw1, h1b, as1, ad1);
  k_conv1<<<25000, 256, 0, stream>>>(rowptr, csr_src, as1, ad1, h1b, b1, hb);
  k_gemm2<<<6250, 256, 0, stream>>>(hb, W2, asw2, adw2, h2b, as2, ad2);
  k_conv2<<<25000, 256, 0, stream>>>(rowptr, csr_src, as2, ad2, h2b, b2, hb,
                                     lng, lnb, wpool, bpool, es);
  k_pool <<<391, 256, 0, stream>>>(hb, es, batch, Ssum, pooled);
  k_head <<<64, 64, 0, stream>>>(pooled, Ssum, wfc1, bfc1, wfc2, bfc2,
                                 (float*)d_out);
}